// Round 2
// baseline (426.159 us; speedup 1.0000x reference)
//
#include <hip/hip_runtime.h>

#define ROWS  4
#define BLOCK 256
#define WPB   (BLOCK / 64)   // waves per block

__global__ __launch_bounds__(BLOCK, 8)   // pin VGPR<=64 -> 8 waves/SIMD possible
void encoder_kernel(const int* __restrict__ nodes,
                    const float* __restrict__ W,    // [V,64]
                    const float* __restrict__ L1,   // [B,64]
                    const float* __restrict__ L2,   // [B,64]
                    const float* __restrict__ AW,   // [128]
                    const float* __restrict__ ABv,  // [1]
                    const float* __restrict__ BW,   // [128]
                    const float* __restrict__ BBv,  // [1]
                    const float* __restrict__ GW,   // [64,64] row-major
                    const float* __restrict__ GB,   // [64]
                    float* __restrict__ out,        // [B,64]
                    int nrows)
{
    const int lane = threadIdx.x & 63;
    const int wid  = threadIdx.x >> 6;

    const float aw_s = AW[lane], aw_l = AW[64 + lane];
    const float bw_s = BW[lane], bw_l = BW[64 + lane];
    const float gb   = GB[lane];
    const float ab   = ABv[0],   bb   = BBv[0];

    // per-wave private LDS slice: no block barrier needed anywhere
    __shared__ float c_lds[WPB][ROWS][64];

    const long totalWaves = (long)gridDim.x * WPB;
    const long nGroups    = (long)nrows / ROWS;

    for (long g = (long)blockIdx.x * WPB + wid; g < nGroups; g += totalWaves) {
        const long row0 = g * ROWS;

        int nidx[ROWS];
#pragma unroll
        for (int r = 0; r < ROWS; ++r) nidx[r] = nodes[row0 + r];

        float sf[ROWS], f1[ROWS], f2[ROWS];
#pragma unroll
        for (int r = 0; r < ROWS; ++r) {
            sf[r] = W[(long)nidx[r] * 64 + lane];
            f1[r] = L1[(row0 + r) * 64 + lane];
            f2[r] = L2[(row0 + r) * 64 + lane];
        }

        // gates: alpha = dot(self, AW[:64]) + dot(l1, AW[64:]) + ab  (PReLU(a=1) = identity)
#pragma unroll
        for (int r = 0; r < ROWS; ++r) {
            float pa = sf[r] * aw_s + f1[r] * aw_l;
            float pb = sf[r] * bw_s + f2[r] * bw_l;
#pragma unroll
            for (int off = 32; off > 0; off >>= 1) {
                pa += __shfl_xor(pa, off);
                pb += __shfl_xor(pb, off);
            }
            const float alpha = pa + ab;
            const float beta  = pb + bb;
            c_lds[wid][r][lane] = sf[r] + alpha * f1[r] + beta * f2[r];
        }
        // wave-internal LDS dependency: compiler inserts lgkmcnt waits; no barrier.

        float acc[ROWS];
#pragma unroll
        for (int r = 0; r < ROWS; ++r) acc[r] = gb;

        // out[d] = sum_k GW[d][k] * c[k]; GW row re-read from L1 (16 KB, resident),
        // c broadcast from LDS (same-address b128 reads, conflict-free)
        const float4* gwp = reinterpret_cast<const float4*>(GW + lane * 64);
#pragma unroll
        for (int k4 = 0; k4 < 16; ++k4) {
            const float4 g4 = gwp[k4];
#pragma unroll
            for (int r = 0; r < ROWS; ++r) {
                const float4 c4 = *reinterpret_cast<const float4*>(&c_lds[wid][r][k4 * 4]);
                acc[r] += g4.x * c4.x;
                acc[r] += g4.y * c4.y;
                acc[r] += g4.z * c4.z;
                acc[r] += g4.w * c4.w;
            }
        }

#pragma unroll
        for (int r = 0; r < ROWS; ++r)
            out[(row0 + r) * 64 + lane] = acc[r];
    }
}

extern "C" void kernel_launch(void* const* d_in, const int* in_sizes, int n_in,
                              void* d_out, int out_size, void* d_ws, size_t ws_size,
                              hipStream_t stream) {
    const int*   nodes = (const int*)  d_in[0];
    const float* W     = (const float*)d_in[1];
    const float* L1    = (const float*)d_in[2];
    const float* L2    = (const float*)d_in[3];
    const float* AW    = (const float*)d_in[4];
    const float* AB    = (const float*)d_in[5];
    const float* BW    = (const float*)d_in[6];
    const float* BB    = (const float*)d_in[7];
    const float* GW    = (const float*)d_in[8];
    const float* GB    = (const float*)d_in[9];
    float* out = (float*)d_out;
    const int nrows = in_sizes[0];  // B = 524288

    dim3 grid(4096), block(BLOCK);
    hipLaunchKernelGGL(encoder_kernel, grid, block, 0, stream,
                       nodes, W, L1, L2, AW, AB, BW, BB, GW, GB, out, nrows);
}

// Round 3
// 165.980 us; speedup vs baseline: 2.5675x; 2.5675x over previous
//
#include <hip/hip_runtime.h>

#define ROWS  4
#define BLOCK 256
#define WPB   (BLOCK / 64)   // waves per block

// (256,4): VGPR cap 128 -> compiler lands at 64 (measured R1), no spill.
// VGPR=64 still allows 32 waves/CU; occupancy comes from grid size instead.
__global__ __launch_bounds__(BLOCK, 4)
void encoder_kernel(const int* __restrict__ nodes,
                    const float* __restrict__ W,    // [V,64]
                    const float* __restrict__ L1,   // [B,64]
                    const float* __restrict__ L2,   // [B,64]
                    const float* __restrict__ AW,   // [128]
                    const float* __restrict__ ABv,  // [1]
                    const float* __restrict__ BW,   // [128]
                    const float* __restrict__ BBv,  // [1]
                    const float* __restrict__ GW,   // [64,64] row-major
                    const float* __restrict__ GB,   // [64]
                    float* __restrict__ out,        // [B,64]
                    int nrows)
{
    const int lane = threadIdx.x & 63;
    const int wid  = threadIdx.x >> 6;

    const float aw_s = AW[lane], aw_l = AW[64 + lane];
    const float bw_s = BW[lane], bw_l = BW[64 + lane];
    const float gb   = GB[lane];
    const float ab   = ABv[0],   bb   = BBv[0];

    // per-wave private LDS slice: no block barrier needed anywhere
    __shared__ float c_lds[WPB][ROWS][64];

    const long totalWaves = (long)gridDim.x * WPB;
    const long nGroups    = (long)nrows / ROWS;

    for (long g = (long)blockIdx.x * WPB + wid; g < nGroups; g += totalWaves) {
        const long row0 = g * ROWS;

        int nidx[ROWS];
#pragma unroll
        for (int r = 0; r < ROWS; ++r) nidx[r] = nodes[row0 + r];

        float sf[ROWS], f1[ROWS], f2[ROWS];
#pragma unroll
        for (int r = 0; r < ROWS; ++r) {
            sf[r] = W[(long)nidx[r] * 64 + lane];
            f1[r] = L1[(row0 + r) * 64 + lane];
            f2[r] = L2[(row0 + r) * 64 + lane];
        }

        // gates: alpha = dot(self, AW[:64]) + dot(l1, AW[64:]) + ab  (PReLU(a=1) = identity)
#pragma unroll
        for (int r = 0; r < ROWS; ++r) {
            float pa = sf[r] * aw_s + f1[r] * aw_l;
            float pb = sf[r] * bw_s + f2[r] * bw_l;
#pragma unroll
            for (int off = 32; off > 0; off >>= 1) {
                pa += __shfl_xor(pa, off);
                pb += __shfl_xor(pb, off);
            }
            const float alpha = pa + ab;
            const float beta  = pb + bb;
            c_lds[wid][r][lane] = sf[r] + alpha * f1[r] + beta * f2[r];
        }
        // wave-internal LDS dependency: compiler inserts lgkmcnt waits; no barrier.

        float acc[ROWS];
#pragma unroll
        for (int r = 0; r < ROWS; ++r) acc[r] = gb;

        // out[d] = sum_k GW[d][k] * c[k]; GW row re-read from L1 (16 KB, resident),
        // c broadcast from LDS (same-address b128 reads, conflict-free)
        const float4* gwp = reinterpret_cast<const float4*>(GW + lane * 64);
#pragma unroll
        for (int k4 = 0; k4 < 16; ++k4) {
            const float4 g4 = gwp[k4];
#pragma unroll
            for (int r = 0; r < ROWS; ++r) {
                const float4 c4 = *reinterpret_cast<const float4*>(&c_lds[wid][r][k4 * 4]);
                acc[r] += g4.x * c4.x;
                acc[r] += g4.y * c4.y;
                acc[r] += g4.z * c4.z;
                acc[r] += g4.w * c4.w;
            }
        }

#pragma unroll
        for (int r = 0; r < ROWS; ++r)
            out[(row0 + r) * 64 + lane] = acc[r];
    }
}

extern "C" void kernel_launch(void* const* d_in, const int* in_sizes, int n_in,
                              void* d_out, int out_size, void* d_ws, size_t ws_size,
                              hipStream_t stream) {
    const int*   nodes = (const int*)  d_in[0];
    const float* W     = (const float*)d_in[1];
    const float* L1    = (const float*)d_in[2];
    const float* L2    = (const float*)d_in[3];
    const float* AW    = (const float*)d_in[4];
    const float* AB    = (const float*)d_in[5];
    const float* BW    = (const float*)d_in[6];
    const float* BB    = (const float*)d_in[7];
    const float* GW    = (const float*)d_in[8];
    const float* GB    = (const float*)d_in[9];
    float* out = (float*)d_out;
    const int nrows = in_sizes[0];  // B = 524288

    dim3 grid(4096), block(BLOCK);
    hipLaunchKernelGGL(encoder_kernel, grid, block, 0, stream,
                       nodes, W, L1, L2, AW, AB, BW, BB, GW, GB, out, nrows);
}